// Round 10
// baseline (18.499 us; speedup 1.0000x reference)
//
#include <hip/hip_runtime.h>

namespace {
constexpr int kB   = 2;
constexpr int kC   = 64;
constexpr int kH   = 128;
constexpr int kW   = 240;
constexpr int kD0  = 16;          // disps 0,3,...,45
constexpr int kD1  = 5;           // disps -2,-1,0,1,2
constexpr int kWc1 = 285;
constexpr int kWc2 = 242;
constexpr int kPad = 48;          // left pad (>= max disp 45)
constexpr int kCols = 144;        // output columns per block (2 blocks per row)
constexpr int kRowL = 196;        // staged row stride in dwords (48+144+4)
constexpr int kF4   = kRowL / 4;  // 49 float4/uint4 per cpair row
constexpr int kCP  = 32;          // channel pairs (64 channels)
constexpr int kGroups   = 3;      // cpair groups {11,11,10}
constexpr int kGThreads = 160;
constexpr int kThreads  = 512;    // 8 waves; 2 blocks/CU -> 16 waves/CU
constexpr int kAcc  = kD0 + kD1;  // 21
constexpr int kSlot = kCols * kAcc;            // 3024 floats per partial slot
constexpr int kOut1 = kB * kD0 * kH * kWc1;
constexpr int kN1   = kD0 * kCols;             // 2304
constexpr int kN2   = kD1 * kCols;             // 720
typedef unsigned int v2u __attribute__((ext_vector_type(2)));
typedef float v2f __attribute__((ext_vector_type(2)));

__device__ __forceinline__ v2f UP(unsigned int x) {   // bf16x2 -> {lo,hi} f32
  v2f f;
  f.x = __uint_as_float(x << 16);
  f.y = __uint_as_float(x & 0xffff0000u);
  return f;
}
__device__ __forceinline__ unsigned int pk2(float lo, float hi) {
  unsigned int r;
  asm("v_cvt_pk_bf16_f32 %0, %1, %2" : "=v"(r) : "v"(lo), "v"(hi));
  return r;
}
__device__ __forceinline__ v2f pfma(v2f a, v2f b, v2f c) {
  return __builtin_elementwise_fma(a, b, c);   // -> v_pk_fma_f32
}
}

__global__ __launch_bounds__(kThreads, 4)     // VGPR cap 128 -> 16 waves/CU
void anynet_disp_kernel(const float* __restrict__ fr, float* __restrict__ out) {
  __shared__ unsigned int E[kCP * kRowL];  // bf16x2 exp(feat_r) window
  __shared__ float P[kGroups * kSlot];     // dedicated partial slots
  const int blk  = blockIdx.x;             // 0..511
  const int half = blk & 1;
  const int bh   = blk >> 1;
  const int b    = bh >> 7;
  const int h    = bh & 127;
  const int colbeg = half * kCols;
  const int tid  = threadIdx.x;

  // ---- phase A: stage exp(feat_r) window [colbeg-48, colbeg+148) as bf16
  // cpairs; OOB = bf16(1.0)=exp(0). Loads unconditional (clamped) -> early issue.
  const float* fr_b = fr + (size_t)b * kC * kH * kW + (size_t)h * kW;
  {
    // 1568 items, 512 threads -> 4 rounds (last partial). Issue all loads first.
    float4 la[4], lb[4];
    int item[4];
    #pragma unroll
    for (int u = 0; u < 4; ++u) {
      const int i = tid + u * kThreads;
      item[u] = i;
      const int cp = i / kF4, lq = i % kF4;
      const int x0 = colbeg - kPad + 4 * lq;
      const int xc = (x0 < 0) ? 0 : (x0 > kW - 4 ? kW - 4 : x0);
      const size_t base = (size_t)(2 * (cp & 31)) * (kH * kW) + xc;
      la[u] = *reinterpret_cast<const float4*>(fr_b + base);
      lb[u] = *reinterpret_cast<const float4*>(fr_b + base + (kH * kW));
    }
    #pragma unroll
    for (int u = 0; u < 4; ++u) {
      const int i = item[u];
      if (i < kCP * kF4) {
        const int cp = i / kF4, lq = i % kF4;
        const int x0 = colbeg - kPad + 4 * lq;
        uint4 w;
        if (x0 >= 0 && x0 + 3 < kW) {
          w.x = pk2(__expf(la[u].x), __expf(lb[u].x));
          w.y = pk2(__expf(la[u].y), __expf(lb[u].y));
          w.z = pk2(__expf(la[u].z), __expf(lb[u].z));
          w.w = pk2(__expf(la[u].w), __expf(lb[u].w));
        } else {
          w = uint4{0x3F803F80u, 0x3F803F80u, 0x3F803F80u, 0x3F803F80u};
        }
        *reinterpret_cast<uint4*>(&E[cp * kRowL + 4 * lq]) = w;
      }
    }
  }
  __syncthreads();

  // ---- phase B: group g owns a cpair slice; thread col t (0..143).
  // Proven 10x ds_read2_b32 tap fetch; packed-f32 math.
  const int g = tid / kGThreads;      // 0..3 (g==3: 32 threads idle)
  const int t = tid % kGThreads;
  v2f acc1[kD0] = {};
  v2f acc2[kD1] = {};
  if (g < kGroups && t < kCols) {
    const int cbeg = (g == 0) ? 0 : (g == 1 ? 11 : 22);
    const int clen = (g < 2) ? 11 : 10;
    unsigned int addr = (unsigned int)(uintptr_t)(const void*)&E[cbeg * kRowL + t + 3];
    for (int cc = 0; cc < clen; ++cc) {
      v2u p0, p1, p2, p3, p4, p5, p6, p7, q0, q1;
      asm volatile(
          "ds_read2_b32 %0, %10 offset0:45 offset1:42\n\t"
          "ds_read2_b32 %1, %10 offset0:39 offset1:36\n\t"
          "ds_read2_b32 %2, %10 offset0:33 offset1:30\n\t"
          "ds_read2_b32 %3, %10 offset0:27 offset1:24\n\t"
          "ds_read2_b32 %4, %10 offset0:21 offset1:18\n\t"
          "ds_read2_b32 %5, %10 offset0:15 offset1:12\n\t"
          "ds_read2_b32 %6, %10 offset0:9 offset1:6\n\t"
          "ds_read2_b32 %7, %10 offset0:3 offset1:0\n\t"
          "ds_read2_b32 %8, %10 offset0:43 offset1:44\n\t"
          "ds_read2_b32 %9, %10 offset0:46 offset1:47\n\t"
          "s_waitcnt lgkmcnt(0)"
          : "=&v"(p0), "=&v"(p1), "=&v"(p2), "=&v"(p3), "=&v"(p4),
            "=&v"(p5), "=&v"(p6), "=&v"(p7), "=&v"(q0), "=&v"(q1)
          : "v"(addr));
      const v2f f0  = UP(p0.x), f1  = UP(p0.y), f2  = UP(p1.x), f3  = UP(p1.y);
      const v2f f4  = UP(p2.x), f5  = UP(p2.y), f6  = UP(p3.x), f7  = UP(p3.y);
      const v2f f8  = UP(p4.x), f9  = UP(p4.y), f10 = UP(p5.x), f11 = UP(p5.y);
      const v2f f12 = UP(p6.x), f13 = UP(p6.y), f14 = UP(p7.x), f15 = UP(p7.y);
      const v2f e0 = UP(q0.x), e1 = UP(q0.y);   // offs 43, 44
      const v2f e2 = UP(q1.x), e3 = UP(q1.y);   // offs 46, 47
      const v2f s = (((f0 + f1) + (f2 + f3)) + ((f4 + f5) + (f6 + f7))) +
                    (((f8 + f9) + (f10 + f11)) + ((f12 + f13) + (f14 + f15)));
      v2f r;
      r.x = __builtin_amdgcn_rcpf(s.x);
      r.y = __builtin_amdgcn_rcpf(s.y);
      acc1[0]  = pfma(f0,  r, acc1[0]);   acc1[1]  = pfma(f1,  r, acc1[1]);
      acc1[2]  = pfma(f2,  r, acc1[2]);   acc1[3]  = pfma(f3,  r, acc1[3]);
      acc1[4]  = pfma(f4,  r, acc1[4]);   acc1[5]  = pfma(f5,  r, acc1[5]);
      acc1[6]  = pfma(f6,  r, acc1[6]);   acc1[7]  = pfma(f7,  r, acc1[7]);
      acc1[8]  = pfma(f8,  r, acc1[8]);   acc1[9]  = pfma(f9,  r, acc1[9]);
      acc1[10] = pfma(f10, r, acc1[10]);  acc1[11] = pfma(f11, r, acc1[11]);
      acc1[12] = pfma(f12, r, acc1[12]);  acc1[13] = pfma(f13, r, acc1[13]);
      acc1[14] = pfma(f14, r, acc1[14]);  acc1[15] = pfma(f15, r, acc1[15]);
      const v2f s2 = ((e0 + e1) + (e2 + e3)) + f0;
      v2f r2;
      r2.x = __builtin_amdgcn_rcpf(s2.x);
      r2.y = __builtin_amdgcn_rcpf(s2.y);
      acc2[0] = pfma(e3, r2, acc2[0]);
      acc2[1] = pfma(e2, r2, acc2[1]);
      acc2[2] = pfma(f0, r2, acc2[2]);
      acc2[3] = pfma(e1, r2, acc2[3]);
      acc2[4] = pfma(e0, r2, acc2[4]);
      addr += kRowL * 4;
    }
  }
  __syncthreads();

  // ---- phase C: each group writes its OWN slot (disjoint, proven)
  if (g < kGroups && t < kCols) {
    float* __restrict__ R = &P[g * kSlot + t * kAcc];  // stride 21: conflict-free
    #pragma unroll
    for (int k = 0; k < kD0; ++k) R[k] = acc1[k].x + acc1[k].y;
    #pragma unroll
    for (int j = 0; j < kD1; ++j) R[kD0 + j] = acc2[j].x + acc2[j].y;
  }
  __syncthreads();

  // ---- phase D: combine 3 slots, coalesced writes
  for (int i = tid; i < kN1 + kN2; i += kThreads) {
    if (i < kN1) {
      const int d  = i / kCols;
      const int t2 = i % kCols;
      const int col = colbeg + t2;
      if (col < kWc1) {
        const int o = t2 * kAcc + d;
        const float v = P[o] + P[kSlot + o] + P[2 * kSlot + o];
        out[((b * kD0 + d) * kH + h) * kWc1 + col] =
            (3.0f * (float)d) * (4.0f + v);            // C/D0 = 4
      }
    } else {
      const int i2 = i - kN1;
      const int j  = i2 / kCols;
      const int t2 = i2 % kCols;
      const int col = colbeg + t2;
      if (col < kWc2) {
        const int o = t2 * kAcc + kD0 + j;
        const float v = P[o] + P[kSlot + o] + P[2 * kSlot + o];
        out[kOut1 + ((b * kD1 + j) * kH + h) * kWc2 + col] =
            (float)(j - 2) * (64.0f / 5.0f + v);       // C/D1 = 12.8
      }
    }
  }
}

extern "C" void kernel_launch(void* const* d_in, const int* in_sizes, int n_in,
                              void* d_out, int out_size, void* d_ws, size_t ws_size,
                              hipStream_t stream) {
  const float* feat_r = (const float*)d_in[1];  // feats_l contributes exactly C/D
  float* out = (float*)d_out;
  anynet_disp_kernel<<<dim3(kB * kH * 2), dim3(kThreads), 0, stream>>>(feat_r, out);
}